// Round 6
// baseline (78.045 us; speedup 1.0000x reference)
//
#include <hip/hip_runtime.h>

// InvertAffine: per sample, trf (12 floats) -> rows of a 3x4 "shift" matrix.
// full = [[A+I, t],[0,1]]; inv(full) = [[Minv, -Minv*t],[0,1]] with M = A+I.
// out = [Minv - I | -Minv*t] flattened (12 floats).
//
// Structure:
//  - Wave-local LDS transpose, 64 samples/wave, ALL LDS traffic as b128:
//    each sample owns SLOTS=5 float4 slots (80 B; rows in slots 0..2, 2 pad).
//    Odd f4-stride => per-sample b128 reads hit all 8 bank-groups across any
//    8 consecutive lanes (conflict-free); scatter writes are <=2-way (free).
//    12 DS instrs/tile/wave vs 48 with a scalar-padded layout.
//  - Depth-1 software pipeline: next tile's 3 global loads issued before the
//    current tile's LDS/compute/store body; last iteration peeled.
//  - Nontemporal loads/stores (data touched exactly once).

typedef float f4 __attribute__((ext_vector_type(4)));

#define TILE 256           // samples per block tile (== blockDim.x)
#define WSAMP 64           // samples per wave
#define SLOTS 5            // f4 slots per sample in LDS (3 used + 2 pad, odd)

__device__ __forceinline__ void invert_rows(const f4 a, const f4 b, const f4 c,
                                            f4* __restrict__ o0,
                                            f4* __restrict__ o1,
                                            f4* __restrict__ o2) {
  const float a00 = a.x + 1.0f, a01 = a.y,        a02 = a.z,        t0 = a.w;
  const float a10 = b.x,        a11 = b.y + 1.0f, a12 = b.z,        t1 = b.w;
  const float a20 = c.x,        a21 = c.y,        a22 = c.z + 1.0f, t2 = c.w;

  const float c00 = a11 * a22 - a12 * a21;
  const float c01 = a12 * a20 - a10 * a22;
  const float c02 = a10 * a21 - a11 * a20;

  const float det  = a00 * c00 + a01 * c01 + a02 * c02;
  const float rdet = 1.0f / det;

  const float i00 = c00 * rdet;
  const float i01 = (a02 * a21 - a01 * a22) * rdet;
  const float i02 = (a01 * a12 - a02 * a11) * rdet;
  const float i10 = c01 * rdet;
  const float i11 = (a00 * a22 - a02 * a20) * rdet;
  const float i12 = (a02 * a10 - a00 * a12) * rdet;
  const float i20 = c02 * rdet;
  const float i21 = (a01 * a20 - a00 * a21) * rdet;
  const float i22 = (a00 * a11 - a01 * a10) * rdet;

  o0->x = i00 - 1.0f; o0->y = i01;        o0->z = i02;
  o0->w = -(i00 * t0 + i01 * t1 + i02 * t2);
  o1->x = i10;        o1->y = i11 - 1.0f; o1->z = i12;
  o1->w = -(i10 * t0 + i11 * t1 + i12 * t2);
  o2->x = i20;        o2->y = i21;        o2->z = i22 - 1.0f;
  o2->w = -(i20 * t0 + i21 * t1 + i22 * t2);
}

__global__ __launch_bounds__(256) void invert_affine_kernel(
    const f4* __restrict__ in, f4* __restrict__ out,
    int nTiles, int B, int per) {
  __shared__ f4 lds[(TILE / WSAMP) * WSAMP * SLOTS];  // 20 KB -> 8 blocks/CU
  const int t = threadIdx.x;
  const int w = t >> 6;   // wave id within block
  const int l = t & 63;   // lane id
  f4* __restrict__ wlds = &lds[w * (WSAMP * SLOTS)];

  // Transposed LDS f4-slot indices for this lane's 3 global float4s.
  int off[3];
#pragma unroll
  for (int k = 0; k < 3; ++k) {
    const int j = k * WSAMP + l;          // float4 index within wave chunk
    const int s = j / 3, r = j - 3 * s;   // sample, row
    off[k] = SLOTS * s + r;
  }
  const int mine = SLOTS * l;             // my sample's first slot

  auto body = [&](const f4 c0, const f4 c1, const f4 c2, long long base) {
    // Phase A: transposed b128 writes of current tile into wave-private LDS
    wlds[off[0]] = c0; wlds[off[1]] = c1; wlds[off[2]] = c2;
    __builtin_amdgcn_wave_barrier();  // cross-lane LDS write->read ordering

    // Phase B: b128 reads of own sample, invert, b128 writeback in place
    const f4 r0 = wlds[mine + 0];
    const f4 r1 = wlds[mine + 1];
    const f4 r2 = wlds[mine + 2];
    f4 o0, o1, o2;
    invert_rows(r0, r1, r2, &o0, &o1, &o2);
    wlds[mine + 0] = o0; wlds[mine + 1] = o1; wlds[mine + 2] = o2;
    __builtin_amdgcn_wave_barrier();  // cross-lane LDS write->read ordering

    // Phase C: b128 reads -> coalesced nontemporal global stores
#pragma unroll
    for (int k = 0; k < 3; ++k)
      __builtin_nontemporal_store(wlds[off[k]], &out[base + k * WSAMP + l]);
    __builtin_amdgcn_wave_barrier();  // next iter's phase A rewrites wlds
  };

  const int tileBeg = blockIdx.x * per;
  int tileEnd = tileBeg + per;
  if (tileEnd > nTiles) tileEnd = nTiles;

  if (tileBeg < tileEnd) {
    // float4 index of this wave's 64-sample chunk within the first tile
    long long base = (long long)tileBeg * (TILE * 3) + w * (WSAMP * 3);

    f4 cur0 = __builtin_nontemporal_load(&in[base + 0 * WSAMP + l]);
    f4 cur1 = __builtin_nontemporal_load(&in[base + 1 * WSAMP + l]);
    f4 cur2 = __builtin_nontemporal_load(&in[base + 2 * WSAMP + l]);

    for (int tile = tileBeg; tile + 1 < tileEnd; ++tile) {
      const long long nb = base + TILE * 3;
      // Next tile's loads stay in flight through the whole body below.
      const f4 n0 = __builtin_nontemporal_load(&in[nb + 0 * WSAMP + l]);
      const f4 n1 = __builtin_nontemporal_load(&in[nb + 1 * WSAMP + l]);
      const f4 n2 = __builtin_nontemporal_load(&in[nb + 2 * WSAMP + l]);
      body(cur0, cur1, cur2, base);
      cur0 = n0; cur1 = n1; cur2 = n2; base = nb;
    }
    body(cur0, cur1, cur2, base);  // peeled last iteration (no next-load)
  }

  // Tail (B not a multiple of TILE): direct strided path, rarely taken.
  const int tailStart = nTiles * TILE;
  for (int i = tailStart + blockIdx.x * (int)blockDim.x + t; i < B;
       i += gridDim.x * blockDim.x) {
    const f4 r0 = in[3 * (long long)i + 0];
    const f4 r1 = in[3 * (long long)i + 1];
    const f4 r2 = in[3 * (long long)i + 2];
    f4 o0, o1, o2;
    invert_rows(r0, r1, r2, &o0, &o1, &o2);
    out[3 * (long long)i + 0] = o0;
    out[3 * (long long)i + 1] = o1;
    out[3 * (long long)i + 2] = o2;
  }
}

extern "C" void kernel_launch(void* const* d_in, const int* in_sizes, int n_in,
                              void* d_out, int out_size, void* d_ws, size_t ws_size,
                              hipStream_t stream) {
  (void)n_in; (void)d_ws; (void)ws_size; (void)out_size;
  const f4* in4 = (const f4*)d_in[0];
  f4* out4 = (f4*)d_out;
  const int B = in_sizes[0] / 12;  // samples
  const int nTiles = B / TILE;

  int blocks = nTiles > 0 ? nTiles : 1;
  if (blocks > 2048) blocks = 2048;  // fully-resident grid (8 blocks/CU)
  const int per = (nTiles + blocks - 1) / blocks;  // contiguous tiles per block

  invert_affine_kernel<<<blocks, 256, 0, stream>>>(in4, out4, nTiles, B, per);
}

// Round 7
// 63.936 us; speedup vs baseline: 1.2207x; 1.2207x over previous
//
#include <hip/hip_runtime.h>

// InvertAffine: per sample, trf (12 floats) -> rows of a 3x4 "shift" matrix.
// full = [[A+I, t],[0,1]]; inv(full) = [[Minv, -Minv*t],[0,1]] with M = A+I.
// out = [Minv - I | -Minv*t] flattened (12 floats).
//
// Structure:
//  - Wave-local LDS transpose, 64 samples/wave, all LDS traffic b128
//    (SLOTS=5 f4 per sample: odd stride -> conflict-free per-sample reads,
//    <=2-way on scatter writes, which is free on CDNA4).
//  - Depth-2 software pipeline: tiles k+1 and k+2 are in flight while tile k
//    is processed (~2 bodies > 900-cyc HBM latency, vs ~1 body at depth-1).
//  - Stores nontemporal (streaming, bypass L2 writeback); loads plain.

typedef float f4 __attribute__((ext_vector_type(4)));

#define TILE 256           // samples per block tile (== blockDim.x)
#define WSAMP 64           // samples per wave
#define SLOTS 5            // f4 slots per sample in LDS (3 used + 2 pad, odd)

__device__ __forceinline__ void invert_rows(const f4 a, const f4 b, const f4 c,
                                            f4* __restrict__ o0,
                                            f4* __restrict__ o1,
                                            f4* __restrict__ o2) {
  const float a00 = a.x + 1.0f, a01 = a.y,        a02 = a.z,        t0 = a.w;
  const float a10 = b.x,        a11 = b.y + 1.0f, a12 = b.z,        t1 = b.w;
  const float a20 = c.x,        a21 = c.y,        a22 = c.z + 1.0f, t2 = c.w;

  const float c00 = a11 * a22 - a12 * a21;
  const float c01 = a12 * a20 - a10 * a22;
  const float c02 = a10 * a21 - a11 * a20;

  const float det  = a00 * c00 + a01 * c01 + a02 * c02;
  const float rdet = 1.0f / det;

  const float i00 = c00 * rdet;
  const float i01 = (a02 * a21 - a01 * a22) * rdet;
  const float i02 = (a01 * a12 - a02 * a11) * rdet;
  const float i10 = c01 * rdet;
  const float i11 = (a00 * a22 - a02 * a20) * rdet;
  const float i12 = (a02 * a10 - a00 * a12) * rdet;
  const float i20 = c02 * rdet;
  const float i21 = (a01 * a20 - a00 * a21) * rdet;
  const float i22 = (a00 * a11 - a01 * a10) * rdet;

  o0->x = i00 - 1.0f; o0->y = i01;        o0->z = i02;
  o0->w = -(i00 * t0 + i01 * t1 + i02 * t2);
  o1->x = i10;        o1->y = i11 - 1.0f; o1->z = i12;
  o1->w = -(i10 * t0 + i11 * t1 + i12 * t2);
  o2->x = i20;        o2->y = i21;        o2->z = i22 - 1.0f;
  o2->w = -(i20 * t0 + i21 * t1 + i22 * t2);
}

__global__ __launch_bounds__(256) void invert_affine_kernel(
    const f4* __restrict__ in, f4* __restrict__ out,
    int nTiles, int B, int per) {
  __shared__ f4 lds[(TILE / WSAMP) * WSAMP * SLOTS];  // 20 KB -> 8 blocks/CU
  const int t = threadIdx.x;
  const int w = t >> 6;   // wave id within block
  const int l = t & 63;   // lane id
  f4* __restrict__ wlds = &lds[w * (WSAMP * SLOTS)];

  // Transposed LDS f4-slot indices for this lane's 3 global float4s.
  int off[3];
#pragma unroll
  for (int k = 0; k < 3; ++k) {
    const int j = k * WSAMP + l;          // float4 index within wave chunk
    const int s = j / 3, r = j - 3 * s;   // sample, row
    off[k] = SLOTS * s + r;
  }
  const int mine = SLOTS * l;             // my sample's first slot

  auto body = [&](const f4 c0, const f4 c1, const f4 c2, long long base) {
    // Phase A: transposed b128 writes of current tile into wave-private LDS
    wlds[off[0]] = c0; wlds[off[1]] = c1; wlds[off[2]] = c2;
    __builtin_amdgcn_wave_barrier();  // cross-lane LDS write->read ordering

    // Phase B: b128 reads of own sample, invert, b128 writeback in place
    const f4 r0 = wlds[mine + 0];
    const f4 r1 = wlds[mine + 1];
    const f4 r2 = wlds[mine + 2];
    f4 o0, o1, o2;
    invert_rows(r0, r1, r2, &o0, &o1, &o2);
    wlds[mine + 0] = o0; wlds[mine + 1] = o1; wlds[mine + 2] = o2;
    __builtin_amdgcn_wave_barrier();  // cross-lane LDS write->read ordering

    // Phase C: b128 reads -> coalesced nontemporal global stores
#pragma unroll
    for (int k = 0; k < 3; ++k)
      __builtin_nontemporal_store(wlds[off[k]], &out[base + k * WSAMP + l]);
    __builtin_amdgcn_wave_barrier();  // next iter's phase A rewrites wlds
  };

  const int tileBeg = blockIdx.x * per;
  int tileEnd = tileBeg + per;
  if (tileEnd > nTiles) tileEnd = nTiles;
  const int n = tileEnd - tileBeg;

  if (n > 0) {
    // float4 index of this wave's 64-sample chunk within the first tile
    const long long base0 = (long long)tileBeg * (TILE * 3) + w * (WSAMP * 3);
    const int STEP = TILE * 3;

    // Prologue: tiles 0 and 1 in flight
    f4 c0, c1, c2, d0, d1, d2;
    c0 = in[base0 + 0 * WSAMP + l];
    c1 = in[base0 + 1 * WSAMP + l];
    c2 = in[base0 + 2 * WSAMP + l];
    if (n > 1) {
      d0 = in[base0 + STEP + 0 * WSAMP + l];
      d1 = in[base0 + STEP + 1 * WSAMP + l];
      d2 = in[base0 + STEP + 2 * WSAMP + l];
    }

    long long base = base0;
    for (int i = 0; i < n; ++i) {
      f4 e0, e1, e2;
      if (i + 2 < n) {  // issue tile i+2 -- stays in flight ~2 bodies
        const long long pb = base + 2LL * STEP;
        e0 = in[pb + 0 * WSAMP + l];
        e1 = in[pb + 1 * WSAMP + l];
        e2 = in[pb + 2 * WSAMP + l];
      }
      body(c0, c1, c2, base);
      c0 = d0; c1 = d1; c2 = d2;
      d0 = e0; d1 = e1; d2 = e2;
      base += STEP;
    }
  }

  // Tail (B not a multiple of TILE): direct strided path, rarely taken.
  const int tailStart = nTiles * TILE;
  for (int i = tailStart + blockIdx.x * (int)blockDim.x + t; i < B;
       i += gridDim.x * blockDim.x) {
    const f4 r0 = in[3 * (long long)i + 0];
    const f4 r1 = in[3 * (long long)i + 1];
    const f4 r2 = in[3 * (long long)i + 2];
    f4 o0, o1, o2;
    invert_rows(r0, r1, r2, &o0, &o1, &o2);
    out[3 * (long long)i + 0] = o0;
    out[3 * (long long)i + 1] = o1;
    out[3 * (long long)i + 2] = o2;
  }
}

extern "C" void kernel_launch(void* const* d_in, const int* in_sizes, int n_in,
                              void* d_out, int out_size, void* d_ws, size_t ws_size,
                              hipStream_t stream) {
  (void)n_in; (void)d_ws; (void)ws_size; (void)out_size;
  const f4* in4 = (const f4*)d_in[0];
  f4* out4 = (f4*)d_out;
  const int B = in_sizes[0] / 12;  // samples
  const int nTiles = B / TILE;

  int blocks = nTiles > 0 ? nTiles : 1;
  if (blocks > 2048) blocks = 2048;  // fully-resident grid (8 blocks/CU)
  const int per = (nTiles + blocks - 1) / blocks;  // contiguous tiles per block

  invert_affine_kernel<<<blocks, 256, 0, stream>>>(in4, out4, nTiles, B, per);
}